// Round 2
// baseline (32080.713 us; speedup 1.0000x reference)
//
#include <hip/hip_runtime.h>
#include <hip/hip_bf16.h>
#include <cstdint>

#define NREG 512
#define NBLK 8
#define RPB  64      // rows per block
#define NTHR 512

typedef unsigned long long u64;
typedef unsigned int u32;

// H(I, a, b, d, big_c) exactly per reference (f32)
__device__ __forceinline__ float Hfun(float I, float a, float b, float d, float bigc) {
    float x = a * I - b;
    float numer = fabsf(x) + 1e-9f;
    float neg = -d * x;
    float denom;
    if (neg > 50.0f) {
        denom = fabsf(1.0f - bigc * neg) + 1e-9f * d;
    } else {
        denom = fabsf(1.0f - expf(fminf(neg, 51.0f))) + 1e-9f * d;
    }
    return numer / denom;
}

__global__ __launch_bounds__(NTHR, 2)
void rww_kernel(const float* __restrict__ init_state,
                const float* __restrict__ Con,
                const float* __restrict__ v_of_T,
                float* __restrict__ out,      // f32: [512*2 state_vals][20000*512*2 hist]
                u64* __restrict__ xslot,      // d_ws: 2 * 512 u64 (tag<<32 | value)
                int nsteps)
{
    __shared__ __align__(16) float sE_lds[NREG];
    __shared__ float part_lds[NTHR];

    const int tid = threadIdx.x;
    const int w   = tid >> 6;      // wave = column chunk (0..7)
    const int l   = tid & 63;      // lane = local row
    const int b   = blockIdx.x;
    const int grow = b * RPB + l;  // global row handled by (any wave, lane l)

    float2* __restrict__ state2 = reinterpret_cast<float2*>(out);          // [512]
    float2* __restrict__ hist2  = reinterpret_cast<float2*>(out + 2 * NREG); // [nsteps*512]

    // ---- load this thread's Con fragment into registers: row grow, cols [w*64, w*64+64) ----
    float4 cw[16];
#pragma unroll
    for (int jj = 0; jj < 16; ++jj) {
        cw[jj] = *reinterpret_cast<const float4*>(Con + (size_t)grow * NREG + w * 64 + jj * 4);
    }

    // ---- initial state ----
    sE_lds[tid] = init_state[2 * tid];     // S_E(0) for region tid
    float sEo = 0.f, sIo = 0.f, vcur = 0.f;
    if (tid < RPB) {
        sEo  = init_state[2 * grow + 0];
        sIo  = init_state[2 * grow + 1];
        vcur = v_of_T[grow];               // v[0][grow]
    }
    __syncthreads();

    for (int t = 0; t < nsteps; ++t) {
        // prefetch next step's noise (hidden behind matvec + poll)
        float vnext = 0.f;
        if (tid < RPB && (t + 1) < nsteps)
            vnext = v_of_T[(size_t)(t + 1) * NREG + grow];

        // ---- matvec partial: row grow, columns chunk w ----
        const float4* s4 = reinterpret_cast<const float4*>(sE_lds) + w * 16;
        float a0 = 0.f, a1 = 0.f, a2 = 0.f, a3 = 0.f;
#pragma unroll
        for (int jj = 0; jj < 16; ++jj) {
            float4 s = s4[jj];             // wave-uniform address -> LDS broadcast
            a0 = fmaf(cw[jj].x, s.x, a0);
            a1 = fmaf(cw[jj].y, s.y, a1);
            a2 = fmaf(cw[jj].z, s.z, a2);
            a3 = fmaf(cw[jj].w, s.w, a3);
        }
        part_lds[w * 64 + l] = (a0 + a1) + (a2 + a3);
        __syncthreads();

        // ---- epilogue on wave 0 (lane = local row) ----
        if (tid < RPB) {
            float net = 0.f;
#pragma unroll
            for (int c = 0; c < 8; ++c) net += part_lds[c * 64 + tid];

            float sE = sEo, sI = sIo;
            float I_E = 0.382f + 0.21f * sE + 3.0f * net - sI;   // W_E*I0 + W_PLUS*J_NMDA*sE + G*J_NMDA*net - J*sI
            float I_I = 0.2674f + 0.15f * sE - sI;               // W_I*I0 + J_NMDA*sE - sI (LAMBDA=0)
            float rE = Hfun(I_E, 310.0f, 125.0f, 0.16f, 1.0e9f);
            float rI = Hfun(I_I, 615.0f, 177.0f, 0.087f, 1.0e5f);
            float dSE = -sE * 0.01f + (1.0f - sE) * 0.000641f * rE + 0.01f * vcur;
            float dSI = -sI * 0.1f + 0.001f * rI + 0.01f * vcur;
            sEo = sE + 1e-4f * dSE;
            sIo = sI + 1e-4f * dSI;

            // publish (value travels atomically with its tag -> no fences needed)
            u64 pk = ((u64)(u32)(t + 1) << 32) | (u64)__float_as_uint(sEo);
            __hip_atomic_store(&xslot[((t + 1) & 1) * NREG + grow], pk,
                               __ATOMIC_RELAXED, __HIP_MEMORY_SCOPE_AGENT);

            // history write (f32 pair)
            hist2[(size_t)t * NREG + grow] = make_float2(sEo, sIo);
            if (t == nsteps - 1) state2[grow] = make_float2(sEo, sIo);

            vcur = vnext;
        }

        // ---- gather next S_E (each thread owns exactly one slot) ----
        if (t + 1 < nsteps) {
            u64* slot = &xslot[((t + 1) & 1) * NREG + tid];
            const u32 want = (u32)(t + 1);
            u64 pk;
            do {
                pk = __hip_atomic_load(slot, __ATOMIC_RELAXED, __HIP_MEMORY_SCOPE_AGENT);
            } while ((u32)(pk >> 32) != want);
            sE_lds[tid] = __uint_as_float((u32)pk);
        }
        __syncthreads();
    }
}

extern "C" void kernel_launch(void* const* d_in, const int* in_sizes, int n_in,
                              void* d_out, int out_size, void* d_ws, size_t ws_size,
                              hipStream_t stream) {
    const float* init_state = (const float*)d_in[0];
    const float* Con        = (const float*)d_in[1];
    const float* v_of_T     = (const float*)d_in[2];
    int nsteps = in_sizes[2] / NREG;   // 20000

    rww_kernel<<<dim3(NBLK), dim3(NTHR), 0, stream>>>(
        init_state, Con, v_of_T, (float*)d_out, (u64*)d_ws, nsteps);
}